// Round 7
// baseline (238.256 us; speedup 1.0000x reference)
//
#include <hip/hip_runtime.h>

using i32x4 = __attribute__((ext_vector_type(4))) int;

#define AS3(p) ((__attribute__((address_space(3))) void*)(p))
#define AS1(p) ((const __attribute__((address_space(1))) void*)(p))

constexpr int M = 8192;
constexpr int N = 4096;
constexpr int K = 4096;
constexpr int BK = 128;          // 128 i8 per row per K-tile = 128 B/row (m201 byte-geometry)
constexpr int NT = K / BK;       // 32 K-tiles

// ---------------- Pass 1a: pack x (int32 -> int8), layout preserved [M][K] ----------------
__global__ void pack_a_kernel(const int4* __restrict__ x, unsigned* __restrict__ a8, int nUnits) {
    int stride = gridDim.x * blockDim.x;
    for (int u = blockIdx.x * blockDim.x + threadIdx.x; u < nUnits; u += stride) {
        int4 v = x[u];
        a8[u] = (v.x & 255) | ((v.y & 255) << 8) | ((v.z & 255) << 16) | (v.w << 24);
    }
}

// ---------------- Pass 1b: pack + transpose W: [K][N] int32 -> [N][K] int8 ----------------
__global__ void pack_wT_kernel(const int* __restrict__ w, char* __restrict__ b8t) {
    __shared__ __align__(16) char T[64][80];
    const int n0 = blockIdx.x * 64;
    const int k0 = blockIdx.y * 64;
    const int tid = threadIdx.x;

    #pragma unroll
    for (int i = 0; i < 4; i++) {
        int u = tid + i * 256;
        int r = u >> 4;
        int c = u & 15;
        int4 v = *(const int4*)&w[(size_t)(k0 + r) * N + n0 + 4 * c];
        T[4 * c + 0][r] = (char)v.x;
        T[4 * c + 1][r] = (char)v.y;
        T[4 * c + 2][r] = (char)v.z;
        T[4 * c + 3][r] = (char)v.w;
    }
    __syncthreads();

    const int n = tid >> 2;
    const int q = tid & 3;
    int4 val = *(const int4*)&T[n][16 * q];
    *(int4*)&b8t[(size_t)(n0 + n) * K + k0 + 16 * q] = val;
}

// ---------------- Pass 2: i8 GEMM, 256x256 tile, BK=128, 4-phase/K-tile interleave ----------------
// 2 LDS slots. Per K-tile: 4 phases {ds_reads (12/4/8/0) | stage | barrier | lgkmcnt(0) |
// setprio(1) | 16 MFMA (one C-quadrant x K=128) | setprio(0) | barrier}. Quadrant order
// (0,0),(0,1),(1,1),(1,0): A/B halves each read ONCE, held in regs across two phases.
// Stage for tile t+1 issues in P0-P1; single vmcnt(0) after P3's MFMAs (~3 phases slack).
// Swizzle (both sides, rule #21): LDS slot (row,c) holds global chunk c ^ (row&7).
// kk=1 K-slice: LDS chunk = c0 XOR 4 -> byte offset c0sw ^ 64 (NOT +64 — R6's bug:
// +64 overflows the 128B row for the 32 lanes with swizzled chunk >= 4).
__global__ __launch_bounds__(512, 2) void gemm_i8_kernel(
    const char* __restrict__ a8, const char* __restrict__ b8t,
    const int* __restrict__ bias, const float* __restrict__ scales,
    float* __restrict__ out)
{
    __shared__ __align__(16) char As[2][256 * BK];   // 32 KB each
    __shared__ __align__(16) char Bs[2][256 * BK];   // total 128 KB -> 1 block/CU

    const int tid  = threadIdx.x;
    const int lane = tid & 63;
    const int wid  = tid >> 6;
    const int wr   = wid >> 2;   // 0..1 -> 128-row band
    const int wc   = wid & 3;    // 0..3 -> 64-col band

    // XCD-aware remap: each XCD covers an 8x8 (tm,tn) square (FETCH 148->98 MB, R3)
    const int bid = blockIdx.x;
    const int xcd = bid & 7;
    const int l   = bid >> 3;
    const int tm  = (xcd >> 1) * 8 + (l >> 3);   // 0..31
    const int tn  = (xcd & 1) * 8 + (l & 7);     // 0..15
    const size_t brow = (size_t)tm * 256;
    const size_t bcol = (size_t)tn * 256;

    // Staging: unit = 64 rows x 128 B = 8 KB; 8 waves cooperate (1 KB each).
    // Wave wid covers rows u*64 + wid*8 + (lane>>3); source chunk pre-swizzled:
    // (lane&7) ^ (row&7) = (lane&7) ^ (lane>>3).
    const int srowS = (wid << 3) + (lane >> 3);
    const int schS  = ((lane & 7) ^ (lane >> 3)) << 4;
    const char* aGs = a8  + (brow + srowS) * (size_t)K + schS;
    const char* bGs = b8t + (bcol + srowS) * (size_t)K + schS;
    const int ldsU = wid * 1024;    // wave-uniform dest within unit; HW adds lane*16

    i32x4 acc[8][4];
    #pragma unroll
    for (int m = 0; m < 8; m++)
        #pragma unroll
        for (int n = 0; n < 4; n++)
            #pragma unroll
            for (int r = 0; r < 4; r++)
                acc[m][n][r] = 0;

    auto stageA = [&](int b, int u, int kt) {
        __builtin_amdgcn_global_load_lds(AS1(aGs + (size_t)(u * 64) * K + (size_t)kt * BK),
                                         AS3(&As[b][u * 8192 + ldsU]), 16, 0, 0);
    };
    auto stageB = [&](int b, int u, int kt) {
        __builtin_amdgcn_global_load_lds(AS1(bGs + (size_t)(u * 64) * K + (size_t)kt * BK),
                                         AS3(&Bs[b][u * 8192 + ldsU]), 16, 0, 0);
    };

    // Fragment reads: row = band + frag*16 + (lane&15); global chunk g = kk*4 + (lane>>4);
    // LDS chunk = g ^ (row&7) = g ^ (lane&7). kk=0: c0sw; kk=1: c1sw = c0sw ^ 64 (XOR!).
    const int frow  = lane & 15;
    const int c0sw  = ((lane >> 4) ^ (lane & 7)) << 4;
    const int c1sw  = c0sw ^ 64;
    const int raBase = wr * 16384 + frow * BK;   // + mh*8192 + m*2048 + c{0,1}sw
    const int rbBase = wc * 8192  + frow * BK;   // + n*2048 + c{0,1}sw

    // Prologue: stage tile 0 fully into slot 0.
    #pragma unroll
    for (int u = 0; u < 4; ++u) { stageA(0, u, 0); stageB(0, u, 0); }
    asm volatile("s_waitcnt vmcnt(0)" ::: "memory");
    __builtin_amdgcn_s_barrier();

    i32x4 aq[4][2], b0[2][2], b1[2][2];   // statically indexed (rule #20)

    for (int t = 0; t < NT; ++t) {
        const int s = t & 1;
        const int o = s ^ 1;
        const char* Ab = &As[s][0] + raBase;
        const char* Bb = &Bs[s][0] + rbBase;

        // ---- P0: stage 4 units; read B0(4) + A-half0(8); MFMA quadrant (mh0,nh0) ----
        if (t + 1 < NT) { stageA(o, 0, t + 1); stageA(o, 1, t + 1); stageB(o, 0, t + 1); stageB(o, 1, t + 1); }
        #pragma unroll
        for (int n = 0; n < 2; ++n) {
            b0[n][0] = *(const i32x4*)(Bb + n * 2048 + c0sw);
            b0[n][1] = *(const i32x4*)(Bb + n * 2048 + c1sw);
        }
        #pragma unroll
        for (int m = 0; m < 4; ++m) {
            aq[m][0] = *(const i32x4*)(Ab + m * 2048 + c0sw);
            aq[m][1] = *(const i32x4*)(Ab + m * 2048 + c1sw);
        }
        __builtin_amdgcn_s_barrier();
        asm volatile("s_waitcnt lgkmcnt(0)" ::: "memory");
        __builtin_amdgcn_sched_barrier(0);
        __builtin_amdgcn_s_setprio(1);
        #pragma unroll
        for (int m = 0; m < 4; ++m)
            #pragma unroll
            for (int n = 0; n < 2; ++n) {
                acc[m][n] = __builtin_amdgcn_mfma_i32_16x16x64_i8(aq[m][0], b0[n][0], acc[m][n], 0, 0, 0);
                acc[m][n] = __builtin_amdgcn_mfma_i32_16x16x64_i8(aq[m][1], b0[n][1], acc[m][n], 0, 0, 0);
            }
        __builtin_amdgcn_s_setprio(0);
        __builtin_amdgcn_s_barrier();

        // ---- P1: stage 4 units; read B1(4); MFMA quadrant (mh0,nh1) ----
        if (t + 1 < NT) { stageA(o, 2, t + 1); stageA(o, 3, t + 1); stageB(o, 2, t + 1); stageB(o, 3, t + 1); }
        #pragma unroll
        for (int n = 0; n < 2; ++n) {
            b1[n][0] = *(const i32x4*)(Bb + (2 + n) * 2048 + c0sw);
            b1[n][1] = *(const i32x4*)(Bb + (2 + n) * 2048 + c1sw);
        }
        __builtin_amdgcn_s_barrier();
        asm volatile("s_waitcnt lgkmcnt(0)" ::: "memory");
        __builtin_amdgcn_sched_barrier(0);
        __builtin_amdgcn_s_setprio(1);
        #pragma unroll
        for (int m = 0; m < 4; ++m)
            #pragma unroll
            for (int n = 0; n < 2; ++n) {
                acc[m][2 + n] = __builtin_amdgcn_mfma_i32_16x16x64_i8(aq[m][0], b1[n][0], acc[m][2 + n], 0, 0, 0);
                acc[m][2 + n] = __builtin_amdgcn_mfma_i32_16x16x64_i8(aq[m][1], b1[n][1], acc[m][2 + n], 0, 0, 0);
            }
        __builtin_amdgcn_s_setprio(0);
        __builtin_amdgcn_s_barrier();

        // ---- P2: read A-half1(8, overwrite aq); MFMA quadrant (mh1,nh1) ----
        #pragma unroll
        for (int m = 0; m < 4; ++m) {
            aq[m][0] = *(const i32x4*)(Ab + 8192 + m * 2048 + c0sw);
            aq[m][1] = *(const i32x4*)(Ab + 8192 + m * 2048 + c1sw);
        }
        __builtin_amdgcn_s_barrier();
        asm volatile("s_waitcnt lgkmcnt(0)" ::: "memory");
        __builtin_amdgcn_sched_barrier(0);
        __builtin_amdgcn_s_setprio(1);
        #pragma unroll
        for (int m = 0; m < 4; ++m)
            #pragma unroll
            for (int n = 0; n < 2; ++n) {
                acc[4 + m][2 + n] = __builtin_amdgcn_mfma_i32_16x16x64_i8(aq[m][0], b1[n][0], acc[4 + m][2 + n], 0, 0, 0);
                acc[4 + m][2 + n] = __builtin_amdgcn_mfma_i32_16x16x64_i8(aq[m][1], b1[n][1], acc[4 + m][2 + n], 0, 0, 0);
            }
        __builtin_amdgcn_s_setprio(0);
        __builtin_amdgcn_s_barrier();

        // ---- P3: no reads; MFMA quadrant (mh1,nh0); vmcnt(0) with ~3 phases of slack ----
        __builtin_amdgcn_s_setprio(1);
        #pragma unroll
        for (int m = 0; m < 4; ++m)
            #pragma unroll
            for (int n = 0; n < 2; ++n) {
                acc[4 + m][n] = __builtin_amdgcn_mfma_i32_16x16x64_i8(aq[m][0], b0[n][0], acc[4 + m][n], 0, 0, 0);
                acc[4 + m][n] = __builtin_amdgcn_mfma_i32_16x16x64_i8(aq[m][1], b0[n][1], acc[4 + m][n], 0, 0, 0);
            }
        __builtin_amdgcn_s_setprio(0);
        asm volatile("s_waitcnt vmcnt(0)" ::: "memory");   // tile t+1 fully landed (issued P0-P1)
        __builtin_amdgcn_s_barrier();
    }

    // epilogue: D col = lane&15 (N-dim), row = (lane>>4)*4 + reg (absmax 0 in r1-r5)
    #pragma unroll
    for (int n = 0; n < 4; ++n) {
        const int col = (int)bcol + wc * 64 + n * 16 + (lane & 15);
        const int bv  = bias[col];
        const float sv = scales[col];
        #pragma unroll
        for (int m = 0; m < 8; ++m) {
            const size_t row0 = brow + wr * 128 + m * 16 + ((lane >> 4) << 2);
            float* o = out + row0 * (size_t)N + col;
            #pragma unroll
            for (int r = 0; r < 4; ++r)
                o[(size_t)r * N] = (float)(acc[m][n][r] + bv) * sv;
        }
    }
}

extern "C" void kernel_launch(void* const* d_in, const int* in_sizes, int n_in,
                              void* d_out, int out_size, void* d_ws, size_t ws_size,
                              hipStream_t stream) {
    const int*   x      = (const int*)d_in[0];
    const int*   w      = (const int*)d_in[1];
    const int*   bias   = (const int*)d_in[2];
    const float* scales = (const float*)d_in[3];
    float* out = (float*)d_out;

    char* a8  = (char*)d_ws;                       // M*K = 32 MB
    char* b8t = a8 + (size_t)M * K;                // N*K = 16 MB

    pack_a_kernel<<<2048, 256, 0, stream>>>((const int4*)x, (unsigned*)a8, M * K / 4);

    dim3 gt(N / 64, K / 64);
    pack_wT_kernel<<<gt, 256, 0, stream>>>(w, b8t);

    gemm_i8_kernel<<<(M / 256) * (N / 256), 512, 0, stream>>>(a8, b8t, bias, scales, out);
}

// Round 8
// 209.068 us; speedup vs baseline: 1.1396x; 1.1396x over previous
//
#include <hip/hip_runtime.h>

using i32x4 = __attribute__((ext_vector_type(4))) int;

#define AS3(p) ((__attribute__((address_space(3))) void*)(p))
#define AS1(p) ((const __attribute__((address_space(1))) void*)(p))

constexpr int M = 8192;
constexpr int N = 4096;
constexpr int K = 4096;
constexpr int BM = 256;
constexpr int BN = 128;
constexpr int BK = 64;           // 64 B/row per K-tile
constexpr int NT = K / BK;       // 64 K-tiles
constexpr int NBUF = 3;          // ring: read t, t+1 landed, t+2 filling

// ---------------- Pass 1a: pack x (int32 -> int8), layout preserved [M][K] ----------------
__global__ void pack_a_kernel(const int4* __restrict__ x, unsigned* __restrict__ a8, int nUnits) {
    int stride = gridDim.x * blockDim.x;
    for (int u = blockIdx.x * blockDim.x + threadIdx.x; u < nUnits; u += stride) {
        int4 v = x[u];
        a8[u] = (v.x & 255) | ((v.y & 255) << 8) | ((v.z & 255) << 16) | (v.w << 24);
    }
}

// ---------------- Pass 1b: pack + transpose W: [K][N] int32 -> [N][K] int8 ----------------
__global__ void pack_wT_kernel(const int* __restrict__ w, char* __restrict__ b8t) {
    __shared__ __align__(16) char T[64][80];
    const int n0 = blockIdx.x * 64;
    const int k0 = blockIdx.y * 64;
    const int tid = threadIdx.x;

    #pragma unroll
    for (int i = 0; i < 4; i++) {
        int u = tid + i * 256;
        int r = u >> 4;
        int c = u & 15;
        int4 v = *(const int4*)&w[(size_t)(k0 + r) * N + n0 + 4 * c];
        T[4 * c + 0][r] = (char)v.x;
        T[4 * c + 1][r] = (char)v.y;
        T[4 * c + 2][r] = (char)v.z;
        T[4 * c + 3][r] = (char)v.w;
    }
    __syncthreads();

    const int n = tid >> 2;
    const int q = tid & 3;
    int4 val = *(const int4*)&T[n][16 * q];
    *(int4*)&b8t[(size_t)(n0 + n) * K + k0 + 16 * q] = val;
}

// ---------------- Pass 2: i8 GEMM, 256x128 tile, 2 blocks/CU, 3-buffer ring ----------------
// Thesis: all 1-block/CU schedules plateau at 8.5-11 B/cyc/CU staging; m97's 21 B/cyc came
// from multi-block co-residency. acc[4][4] (64 regs) + launch_bounds(512,4) caps regs at 128
// -> 4 waves/SIMD -> 2 independent blocks/CU; block A's MFMA hides block B's staging/drain.
// LDS 72 KB/block (A 3x16K + B 3x8K) -> 2x72=144 <= 160 KB. Ring: stage(t+2) at tile t,
// counted vmcnt(3) at tile end (never 0 mid-loop), drain distance = 1 full tile.
// Both-sides chunk swizzle (PMC-verified 0 conflicts since R2).
__global__ __launch_bounds__(512, 4) void gemm_i8_kernel(
    const char* __restrict__ a8, const char* __restrict__ b8t,
    const int* __restrict__ bias, const float* __restrict__ scales,
    float* __restrict__ out)
{
    __shared__ __align__(16) char As[NBUF][BM * BK];   // 16 KB each
    __shared__ __align__(16) char Bs[NBUF][BN * BK];   // 8 KB each

    const int tid  = threadIdx.x;
    const int lane = tid & 63;
    const int wid  = tid >> 6;
    const int wr   = wid >> 1;   // 0..3 -> 64-row band
    const int wc   = wid & 1;    // 0..1 -> 64-col band

    // XCD-aware remap: each XCD covers an 8tm x 16tn chunk.
    // Per-K-step L2 window: A 8*256*64B = 128 KB + B 16*128*64B = 128 KB -> fits L2.
    const int bid = blockIdx.x;               // grid = 32*32 = 1024
    const int xcd = bid & 7;
    const int l   = bid >> 3;                 // 0..127
    const int tm  = (xcd >> 1) * 8 + (l >> 4);   // 0..31
    const int tn  = (xcd & 1) * 16 + (l & 15);   // 0..31
    const size_t brow = (size_t)tm * BM;
    const size_t bcol = (size_t)tn * BN;

    // Staging: 3 loads/thread/tile (A rows r, r+128; B row r), r = tid>>2 (0..127).
    // Source chunk (tid&3) ^ ((r>>1)&3) pre-swizzled (rule #21: linear LDS dest).
    const int srow = tid >> 2;
    const int schS = ((tid & 3) ^ ((tid >> 3) & 3)) << 4;
    const char* aGs = a8  + (brow + srow) * (size_t)K + schS;
    const char* bGs = b8t + (bcol + srow) * (size_t)K + schS;
    const int ldsW = wid * 1024;   // wave-uniform dest; HW adds lane*16

    i32x4 acc[4][4];
    #pragma unroll
    for (int m = 0; m < 4; m++)
        #pragma unroll
        for (int n = 0; n < 4; n++)
            #pragma unroll
            for (int r = 0; r < 4; r++)
                acc[m][n][r] = 0;

    auto stage = [&](int slot, int kt) {
        const char* a = aGs + (size_t)kt * BK;
        const char* b = bGs + (size_t)kt * BK;
        __builtin_amdgcn_global_load_lds(AS1(a),                  AS3(&As[slot][ldsW]),        16, 0, 0);
        __builtin_amdgcn_global_load_lds(AS1(a + (size_t)128*K),  AS3(&As[slot][8192 + ldsW]), 16, 0, 0);
        __builtin_amdgcn_global_load_lds(AS1(b),                  AS3(&Bs[slot][ldsW]),        16, 0, 0);
    };

    // Fragment reads: row = band + f*16 + frow; chunk c = lane>>4 swizzled by ((frow>>1)&3).
    const int frow = lane & 15;
    const int c0sw = ((lane >> 4) ^ ((frow >> 1) & 3)) << 4;
    const int raOff = wr * 4096 + frow * 64 + c0sw;
    const int rbOff = wc * 4096 + frow * 64 + c0sw;

    // Prologue: fill slots 0,1; wait slot 0 only (slot 1 stays in flight).
    stage(0, 0);
    stage(1, 1);
    asm volatile("s_waitcnt vmcnt(3)" ::: "memory");
    __builtin_amdgcn_s_barrier();

    int s = 0;
    for (int t = 0; t < NT; ++t) {
        int sp = s - 1; if (sp < 0) sp = 2;        // (t+2) % 3
        const bool more = (t + 2 < NT);
        if (more) stage(sp, t + 2);

        const char* Ab = &As[s][0] + raOff;
        const char* Bb = &Bs[s][0] + rbOff;

        i32x4 bfr[4];
        #pragma unroll
        for (int n = 0; n < 4; ++n)
            bfr[n] = *(const i32x4*)(Bb + n * 1024);

        __builtin_amdgcn_s_setprio(1);
        #pragma unroll
        for (int m = 0; m < 4; ++m) {
            i32x4 af = *(const i32x4*)(Ab + m * 1024);   // compiler inserts counted lgkmcnt
            #pragma unroll
            for (int n = 0; n < 4; ++n)
                acc[m][n] = __builtin_amdgcn_mfma_i32_16x16x64_i8(af, bfr[n], acc[m][n], 0, 0, 0);
        }
        __builtin_amdgcn_s_setprio(0);

        // my reads of slot s done (WAR: slot s is overwritten by stage at t+1)
        asm volatile("s_waitcnt lgkmcnt(0)" ::: "memory");
        // counted drain: t+2's 3 loads stay in flight; t+1's (issued last tile) must land
        if (more) asm volatile("s_waitcnt vmcnt(3)" ::: "memory");
        else      asm volatile("s_waitcnt vmcnt(0)" ::: "memory");
        __builtin_amdgcn_s_barrier();

        s = (s == 2) ? 0 : s + 1;
    }

    // epilogue: D col = lane&15 (N-dim), row = (lane>>4)*4 + reg (absmax 0 in r1-r7)
    #pragma unroll
    for (int n = 0; n < 4; ++n) {
        const int col = (int)bcol + wc * 64 + n * 16 + (lane & 15);
        const int bv  = bias[col];
        const float sv = scales[col];
        #pragma unroll
        for (int m = 0; m < 4; ++m) {
            const size_t row0 = brow + wr * 64 + m * 16 + ((lane >> 4) << 2);
            float* o = out + row0 * (size_t)N + col;
            #pragma unroll
            for (int r = 0; r < 4; ++r)
                o[(size_t)r * N] = (float)(acc[m][n][r] + bv) * sv;
        }
    }
}

extern "C" void kernel_launch(void* const* d_in, const int* in_sizes, int n_in,
                              void* d_out, int out_size, void* d_ws, size_t ws_size,
                              hipStream_t stream) {
    const int*   x      = (const int*)d_in[0];
    const int*   w      = (const int*)d_in[1];
    const int*   bias   = (const int*)d_in[2];
    const float* scales = (const float*)d_in[3];
    float* out = (float*)d_out;

    char* a8  = (char*)d_ws;                       // M*K = 32 MB
    char* b8t = a8 + (size_t)M * K;                // N*K = 16 MB

    pack_a_kernel<<<2048, 256, 0, stream>>>((const int4*)x, (unsigned*)a8, M * K / 4);

    dim3 gt(N / 64, K / 64);
    pack_wT_kernel<<<gt, 256, 0, stream>>>(w, b8t);

    gemm_i8_kernel<<<(M / BM) * (N / BN), 512, 0, stream>>>(a8, b8t, bias, scales, out);
}